// Round 4
// baseline (198.218 us; speedup 1.0000x reference)
//
#include <hip/hip_runtime.h>
#include <stdint.h>

// Batched kNN (k=20, D=3) vs an fp32 numpy/XLA-CPU reference.
// Primary rank key: fp32 dist, chains matching BLAS sgemm K=3:
//   sq  = ((x0*x0 + x1*x1) + x2*x2)          plain (np.sum / XLA reduce)
//   dot = fmaf(x2,y2, fmaf(x1,y1, x0*y0))    FMA ascending-k (sgemm/Eigen)
//   d   = (sq_i + sq_j) - 2*dot
// Exact fp32 ties (sub-ulp true gaps) are re-ranked by the TRUE distance in
// fp64 (exact products on fp32 inputs => no chain ambiguity), then by index.
// k+1=21 candidates are selected so a tie straddling the rank-19/20 boundary
// is refined correctly.

#define MAXC 32  // candidates per lane -> supports cloud size <= 2048 (actual ~1536)

__global__ void knn_precompute_kernel(const float* __restrict__ x,
                                      const int* __restrict__ batch,
                                      int n,
                                      float4* __restrict__ pts,
                                      double* __restrict__ sqd,
                                      int* __restrict__ starts,
                                      int* __restrict__ ends) {
#pragma clang fp contract(off)
    int j = blockIdx.x * blockDim.x + threadIdx.x;
    if (j >= n) return;
    float x0 = x[3 * j + 0];
    float x1 = x[3 * j + 1];
    float x2 = x[3 * j + 2];
    float sq = x0 * x0 + x1 * x1 + x2 * x2;  // plain chain
    pts[j] = make_float4(x0, x1, x2, sq);
    double p0 = (double)x0 * (double)x0;     // exact
    double p1 = (double)x1 * (double)x1;
    double p2 = (double)x2 * (double)x2;
    sqd[j] = (p0 + p1) + p2;
    int b = batch[j];
    if (j == 0 || batch[j - 1] != b) starts[b] = j;
    if (j == n - 1 || batch[j + 1] != b) ends[b] = j + 1;
}

__device__ __forceinline__ unsigned long long map64(double d) {
    unsigned long long u = __double_as_longlong(d);
    return u ^ (unsigned long long)(((long long)u >> 63) |
                                    (long long)0x8000000000000000ull);
}

__global__ __launch_bounds__(64) void knn_select_kernel(
        const float4* __restrict__ pts,
        const double* __restrict__ sqd,
        const int* __restrict__ batch,
        const int* __restrict__ starts,
        const int* __restrict__ ends,
        int k,
        int* __restrict__ out) {
#pragma clang fp contract(off)
    const int i = blockIdx.x;       // one row (query point) per block
    const int lane = threadIdx.x;   // 64 lanes = 1 wave

    const int b = batch[i];
    const int s0 = starts[b];
    const int e0 = ends[b];

    const float4 wi = pts[i];
    const float sqi = wi.w;

    // Per-lane candidate keys: (monotonic_f32(dist) << 32) | index.
    unsigned long long slots[MAXC];
#pragma unroll
    for (int t = 0; t < MAXC; ++t) {
        const int j = s0 + lane + t * 64;
        unsigned long long key = ~0ull;  // padding: larger than any real key
        if (j < e0) {
            const float4 wj = pts[j];
            float dot = __builtin_fmaf(wi.z, wj.z,
                        __builtin_fmaf(wi.y, wj.y, wi.x * wj.x));
            float d = (sqi + wj.w) - 2.0f * dot;
            unsigned int u = __float_as_uint(d);
            unsigned int m = u ^ (unsigned int)(((int)u >> 31) | 0x80000000);
            key = ((unsigned long long)m << 32) | (unsigned int)j;
        }
        slots[t] = key;
    }

    // Select k+1 winners; lane r keeps the r-th smallest key.
    const int kk = k + 1;  // 21
    unsigned long long sel = ~0ull;
    for (int r = 0; r < kk; ++r) {
        unsigned long long m = slots[0];
#pragma unroll
        for (int t = 1; t < MAXC; ++t) {
            unsigned long long v = slots[t];
            m = (v < m) ? v : m;
        }
#pragma unroll
        for (int off = 32; off > 0; off >>= 1) {
            unsigned long long o = __shfl_xor(m, off);
            m = (o < m) ? o : m;
        }
        if (lane == r) sel = m;
#pragma unroll
        for (int t = 0; t < MAXC; ++t) {
            if (slots[t] == m) slots[t] = ~0ull;
        }
    }

    // Refinement: re-rank the kk winners by (fp32key, fp64 dist, idx).
    const int valid = (lane < kk) && (sel != ~0ull);
    const unsigned int v32 = (unsigned int)(sel >> 32);     // mapped fp32 dist
    const int idx = (int)(unsigned int)sel;                 // candidate index
    unsigned long long m64 = ~0ull;
    if (valid) {
        const float4 wj = pts[idx];
        double p0 = (double)wi.x * (double)wj.x;  // exact
        double p1 = (double)wi.y * (double)wj.y;
        double p2 = (double)wi.z * (double)wj.z;
        double dot = (p0 + p1) + p2;
        double d64 = (sqd[i] + sqd[idx]) - 2.0 * dot;
        m64 = map64(d64);
    }

    int pos = 0;
    for (int s = 0; s < kk; ++s) {
        unsigned int vs = (unsigned int)__shfl((int)v32, s);
        unsigned long long ms = __shfl(m64, s);
        int is_ = __shfl(idx, s);
        int vld = __shfl(valid, s);
        bool less = (vs < v32) ||
                    (vs == v32 && (ms < m64 || (ms == m64 && is_ < idx)));
        if (vld && less) ++pos;
    }

    if (valid && pos < k) out[(long long)i * k + pos] = idx;
}

extern "C" void kernel_launch(void* const* d_in, const int* in_sizes, int n_in,
                              void* d_out, int out_size, void* d_ws, size_t ws_size,
                              hipStream_t stream) {
    const float* x = (const float*)d_in[0];
    const int* batch = (const int*)d_in[1];
    const int n = in_sizes[1];            // 12288 points
    const int k = out_size / n;           // 20

    char* ws = (char*)d_ws;
    float4* pts = (float4*)ws;                     ws += (size_t)n * sizeof(float4);
    double* sqd = (double*)ws;                     ws += (size_t)n * sizeof(double);
    int* starts = (int*)ws;                        ws += 256 * sizeof(int);
    int* ends = (int*)ws;
    int* out = (int*)d_out;

    knn_precompute_kernel<<<(n + 255) / 256, 256, 0, stream>>>(x, batch, n, pts, sqd, starts, ends);
    knn_select_kernel<<<n, 64, 0, stream>>>(pts, sqd, batch, starts, ends, k, out);
}

// Round 5
// 178.049 us; speedup vs baseline: 1.1133x; 1.1133x over previous
//
#include <hip/hip_runtime.h>
#include <stdint.h>

// Batched kNN (k=20, D=3) vs fp32 numpy/XLA-CPU reference. Numerics LOCKED
// (R4 passed absmax=0):
//   sq  = ((x0*x0 + x1*x1) + x2*x2)          plain chain
//   dot = fmaf(x2,y2, fmaf(x1,y1, x0*y0))    FMA ascending-k
//   d   = (sq_i + sq_j) - 2*dot
// fp32 ties re-ranked by exact fp64 distance, then index; k+1=21 selected.
//
// R5 perf changes: 4 rows per 256-thread block (1 row/wave) to beat the
// ~16-workgroup/CU occupancy cap; MAXC 32->28 (supports cloud<=1792,
// actual 1536 +- ~37, +7 sigma headroom) keeping full unroll so slots[]
// stays in registers.

#define MAXC 28
#define ROWS_PER_BLOCK 4

__global__ void knn_precompute_kernel(const float* __restrict__ x,
                                      const int* __restrict__ batch,
                                      int n,
                                      float4* __restrict__ pts,
                                      double* __restrict__ sqd,
                                      int* __restrict__ starts,
                                      int* __restrict__ ends) {
#pragma clang fp contract(off)
    int j = blockIdx.x * blockDim.x + threadIdx.x;
    if (j >= n) return;
    float x0 = x[3 * j + 0];
    float x1 = x[3 * j + 1];
    float x2 = x[3 * j + 2];
    float sq = x0 * x0 + x1 * x1 + x2 * x2;  // plain chain
    pts[j] = make_float4(x0, x1, x2, sq);
    double p0 = (double)x0 * (double)x0;     // exact
    double p1 = (double)x1 * (double)x1;
    double p2 = (double)x2 * (double)x2;
    sqd[j] = (p0 + p1) + p2;
    int b = batch[j];
    if (j == 0 || batch[j - 1] != b) starts[b] = j;
    if (j == n - 1 || batch[j + 1] != b) ends[b] = j + 1;
}

__device__ __forceinline__ unsigned long long map64(double d) {
    unsigned long long u = __double_as_longlong(d);
    return u ^ (unsigned long long)(((long long)u >> 63) |
                                    (long long)0x8000000000000000ull);
}

__global__ __launch_bounds__(256) void knn_select_kernel(
        const float4* __restrict__ pts,
        const double* __restrict__ sqd,
        const int* __restrict__ batch,
        const int* __restrict__ starts,
        const int* __restrict__ ends,
        int k, int n,
        int* __restrict__ out) {
#pragma clang fp contract(off)
    const int wave = threadIdx.x >> 6;
    const int lane = threadIdx.x & 63;
    const int i = blockIdx.x * ROWS_PER_BLOCK + wave;  // one row per wave
    if (i >= n) return;

    const int b = batch[i];
    const int s0 = starts[b];
    const int e0 = ends[b];

    const float4 wi = pts[i];
    const float sqi = wi.w;

    // Per-lane candidate keys: (monotonic_f32(dist) << 32) | index.
    unsigned long long slots[MAXC];
#pragma unroll
    for (int t = 0; t < MAXC; ++t) {
        const int j = s0 + lane + t * 64;
        unsigned long long key = ~0ull;  // padding: larger than any real key
        if (j < e0) {
            const float4 wj = pts[j];
            float dot = __builtin_fmaf(wi.z, wj.z,
                        __builtin_fmaf(wi.y, wj.y, wi.x * wj.x));
            float d = (sqi + wj.w) - 2.0f * dot;
            unsigned int u = __float_as_uint(d);
            unsigned int m = u ^ (unsigned int)(((int)u >> 31) | 0x80000000);
            key = ((unsigned long long)m << 32) | (unsigned int)j;
        }
        slots[t] = key;
    }

    // Select k+1 winners; lane r keeps the r-th smallest key.
    const int kk = k + 1;  // 21
    unsigned long long sel = ~0ull;
    for (int r = 0; r < kk; ++r) {
        unsigned long long m = slots[0];
#pragma unroll
        for (int t = 1; t < MAXC; ++t) {
            unsigned long long v = slots[t];
            m = (v < m) ? v : m;
        }
#pragma unroll
        for (int off = 32; off > 0; off >>= 1) {
            unsigned long long o = __shfl_xor(m, off);
            m = (o < m) ? o : m;
        }
        if (lane == r) sel = m;
#pragma unroll
        for (int t = 0; t < MAXC; ++t) {
            if (slots[t] == m) slots[t] = ~0ull;
        }
    }

    // Refinement: re-rank the kk winners by (fp32key, fp64 dist, idx).
    const int valid = (lane < kk) && (sel != ~0ull);
    const unsigned int v32 = (unsigned int)(sel >> 32);     // mapped fp32 dist
    const int idx = (int)(unsigned int)sel;                 // candidate index
    unsigned long long m64 = ~0ull;
    if (valid) {
        const float4 wj = pts[idx];
        double p0 = (double)wi.x * (double)wj.x;  // exact
        double p1 = (double)wi.y * (double)wj.y;
        double p2 = (double)wi.z * (double)wj.z;
        double dot = (p0 + p1) + p2;
        double d64 = (sqd[i] + sqd[idx]) - 2.0 * dot;
        m64 = map64(d64);
    }

    int pos = 0;
    for (int s = 0; s < kk; ++s) {
        unsigned int vs = (unsigned int)__shfl((int)v32, s);
        unsigned long long ms = __shfl(m64, s);
        int is_ = __shfl(idx, s);
        int vld = __shfl(valid, s);
        bool less = (vs < v32) ||
                    (vs == v32 && (ms < m64 || (ms == m64 && is_ < idx)));
        if (vld && less) ++pos;
    }

    if (valid && pos < k) out[(long long)i * k + pos] = idx;
}

extern "C" void kernel_launch(void* const* d_in, const int* in_sizes, int n_in,
                              void* d_out, int out_size, void* d_ws, size_t ws_size,
                              hipStream_t stream) {
    const float* x = (const float*)d_in[0];
    const int* batch = (const int*)d_in[1];
    const int n = in_sizes[1];            // 12288 points
    const int k = out_size / n;           // 20

    char* ws = (char*)d_ws;
    float4* pts = (float4*)ws;                     ws += (size_t)n * sizeof(float4);
    double* sqd = (double*)ws;                     ws += (size_t)n * sizeof(double);
    int* starts = (int*)ws;                        ws += 256 * sizeof(int);
    int* ends = (int*)ws;
    int* out = (int*)d_out;

    knn_precompute_kernel<<<(n + 255) / 256, 256, 0, stream>>>(x, batch, n, pts, sqd, starts, ends);
    const int blocks = (n + ROWS_PER_BLOCK - 1) / ROWS_PER_BLOCK;
    knn_select_kernel<<<blocks, 64 * ROWS_PER_BLOCK, 0, stream>>>(pts, sqd, batch, starts, ends, k, n, out);
}

// Round 6
// 116.276 us; speedup vs baseline: 1.7047x; 1.5313x over previous
//
#include <hip/hip_runtime.h>
#include <stdint.h>

// Batched kNN (k=20, D=3) vs fp32 numpy/XLA-CPU reference. Numerics LOCKED
// (R4 passed absmax=0):
//   sq  = ((x0*x0 + x1*x1) + x2*x2)          plain chain
//   dot = fmaf(x2,y2, fmaf(x1,y1, x0*y0))    FMA ascending-k
//   d   = (sq_i + sq_j) - 2*dot
// fp32 ties re-ranked by exact fp64 distance, then index.
//
// R6 structure: 3-phase select.
//  P1: u32 extract-min, k rounds, GROUP invalidation (all slots == round min
//      -> 0xFFFFFFFF). 20 distinct values extracted => every candidate with
//      value <= value(rank-19) incl. all its fp32 ties is marked.
//  P2: ballot/mbcnt compaction of marked slots' indices into LDS (~20-24).
//  P3: R4's proven refinement: rank collected by (fp32key, fp64 dist, idx).

#define MAXC 28            // supports cloud <= 1792 (actual ~1536 +- 37)
#define ROWS_PER_BLOCK 4   // 1 row per wave, 256-thread blocks

__global__ void knn_precompute_kernel(const float* __restrict__ x,
                                      const int* __restrict__ batch,
                                      int n,
                                      float4* __restrict__ pts,
                                      double* __restrict__ sqd,
                                      int* __restrict__ starts,
                                      int* __restrict__ ends) {
#pragma clang fp contract(off)
    int j = blockIdx.x * blockDim.x + threadIdx.x;
    if (j >= n) return;
    float x0 = x[3 * j + 0];
    float x1 = x[3 * j + 1];
    float x2 = x[3 * j + 2];
    float sq = x0 * x0 + x1 * x1 + x2 * x2;  // plain chain
    pts[j] = make_float4(x0, x1, x2, sq);
    double p0 = (double)x0 * (double)x0;     // exact
    double p1 = (double)x1 * (double)x1;
    double p2 = (double)x2 * (double)x2;
    sqd[j] = (p0 + p1) + p2;
    int b = batch[j];
    if (j == 0 || batch[j - 1] != b) starts[b] = j;
    if (j == n - 1 || batch[j + 1] != b) ends[b] = j + 1;
}

__device__ __forceinline__ unsigned long long map64(double d) {
    unsigned long long u = __double_as_longlong(d);
    return u ^ (unsigned long long)(((long long)u >> 63) |
                                    (long long)0x8000000000000000ull);
}

__device__ __forceinline__ unsigned int map32(float d) {
    unsigned int u = __float_as_uint(d);
    return u ^ (unsigned int)(((int)u >> 31) | 0x80000000);
}

__global__ __launch_bounds__(256) void knn_select_kernel(
        const float4* __restrict__ pts,
        const double* __restrict__ sqd,
        const int* __restrict__ batch,
        const int* __restrict__ starts,
        const int* __restrict__ ends,
        int k, int n,
        int* __restrict__ out) {
#pragma clang fp contract(off)
    __shared__ int coll[ROWS_PER_BLOCK][64];
    const int wave = threadIdx.x >> 6;
    const int lane = threadIdx.x & 63;
    const int i = blockIdx.x * ROWS_PER_BLOCK + wave;  // one row per wave
    if (i >= n) return;

    const int b = batch[i];
    const int s0 = starts[b];
    const int e0 = ends[b];

    const float4 wi = pts[i];
    const float sqi = wi.w;

    // Build u32 value keys (mapped fp32 distance), lane-cyclic layout.
    unsigned int slots[MAXC];
#pragma unroll
    for (int t = 0; t < MAXC; ++t) {
        const int j = s0 + lane + t * 64;
        unsigned int key = 0xFFFFFFFFu;  // pad > any real mapped value
        if (j < e0) {
            const float4 wj = pts[j];
            float dot = __builtin_fmaf(wi.z, wj.z,
                        __builtin_fmaf(wi.y, wj.y, wi.x * wj.x));
            float d = (sqi + wj.w) - 2.0f * dot;
            key = map32(d);
        }
        slots[t] = key;
    }

    // Phase 1: k rounds of distinct-value extract-min with group invalidate.
    for (int r = 0; r < k; ++r) {
        // 4 independent min chains for ILP, then combine.
        unsigned int m0 = slots[0], m1 = slots[1], m2 = slots[2], m3 = slots[3];
#pragma unroll
        for (int t = 4; t < MAXC; t += 4) {
            m0 = min(m0, slots[t + 0]);
            m1 = min(m1, slots[t + 1]);
            m2 = min(m2, slots[t + 2]);
            m3 = min(m3, slots[t + 3]);
        }
        unsigned int lm = min(min(m0, m1), min(m2, m3));
        // 64-lane butterfly min (u32: 1 shfl + 1 min per stage).
#pragma unroll
        for (int off = 32; off > 0; off >>= 1)
            lm = min(lm, (unsigned int)__shfl_xor((int)lm, off));
        // Invalidate the whole value-group of the winner.
#pragma unroll
        for (int t = 0; t < MAXC; ++t)
            if (slots[t] == lm) slots[t] = 0xFFFFFFFFu;
    }

    // Phase 2: compact indices of extracted slots into LDS.
    int base = 0;
#pragma unroll
    for (int t = 0; t < MAXC; ++t) {
        const int j = s0 + lane + t * 64;
        bool hit = (slots[t] == 0xFFFFFFFFu) && (j < e0);
        unsigned long long bal = __ballot(hit);
        int off = base + __builtin_amdgcn_mbcnt_hi(
                             (unsigned int)(bal >> 32),
                             __builtin_amdgcn_mbcnt_lo((unsigned int)bal, 0));
        if (hit && off < 64) coll[wave][off] = j;
        base += (int)__popcll(bal);
    }
    const int cnt = min(base, 64);  // wave-uniform

    // Phase 3: refinement — rank collected by (fp32key, fp64 dist, idx).
    const bool valid = (lane < cnt);
    const int idx = valid ? coll[wave][lane] : 0;
    unsigned int v32 = 0xFFFFFFFFu;
    unsigned long long m64 = ~0ull;
    if (valid) {
        const float4 wj = pts[idx];
        float dot = __builtin_fmaf(wi.z, wj.z,
                    __builtin_fmaf(wi.y, wj.y, wi.x * wj.x));
        float d = (sqi + wj.w) - 2.0f * dot;
        v32 = map32(d);
        double p0 = (double)wi.x * (double)wj.x;  // exact
        double p1 = (double)wi.y * (double)wj.y;
        double p2 = (double)wi.z * (double)wj.z;
        double dot64 = (p0 + p1) + p2;
        double d64 = (sqd[i] + sqd[idx]) - 2.0 * dot64;
        m64 = map64(d64);
    }

    int pos = 0;
    for (int s = 0; s < cnt; ++s) {
        unsigned int vs = (unsigned int)__shfl((int)v32, s);
        unsigned long long ms = __shfl(m64, s);
        int is_ = __shfl(idx, s);
        bool less = (vs < v32) ||
                    (vs == v32 && (ms < m64 || (ms == m64 && is_ < idx)));
        pos += less ? 1 : 0;
    }

    if (valid && pos < k) out[(long long)i * k + pos] = idx;
}

extern "C" void kernel_launch(void* const* d_in, const int* in_sizes, int n_in,
                              void* d_out, int out_size, void* d_ws, size_t ws_size,
                              hipStream_t stream) {
    const float* x = (const float*)d_in[0];
    const int* batch = (const int*)d_in[1];
    const int n = in_sizes[1];            // 12288 points
    const int k = out_size / n;           // 20

    char* ws = (char*)d_ws;
    float4* pts = (float4*)ws;                     ws += (size_t)n * sizeof(float4);
    double* sqd = (double*)ws;                     ws += (size_t)n * sizeof(double);
    int* starts = (int*)ws;                        ws += 256 * sizeof(int);
    int* ends = (int*)ws;
    int* out = (int*)d_out;

    knn_precompute_kernel<<<(n + 255) / 256, 256, 0, stream>>>(x, batch, n, pts, sqd, starts, ends);
    const int blocks = (n + ROWS_PER_BLOCK - 1) / ROWS_PER_BLOCK;
    knn_select_kernel<<<blocks, 64 * ROWS_PER_BLOCK, 0, stream>>>(pts, sqd, batch, starts, ends, k, n, out);
}

// Round 8
// 101.399 us; speedup vs baseline: 1.9548x; 1.1467x over previous
//
#include <hip/hip_runtime.h>
#include <stdint.h>

// Batched kNN (k=20, D=3) vs fp32 numpy/XLA-CPU reference. Numerics LOCKED
// (R4 passed absmax=0):
//   sq  = ((x0*x0 + x1*x1) + x2*x2)          plain chain
//   dot = fmaf(x2,y2, fmaf(x1,y1, x0*y0))    FMA ascending-k
//   d   = (sq_i + sq_j) - 2*dot
// fp32 ties re-ranked by exact fp64 distance, then index.
//
// R8 = R7 + OOB fix in wave_lower_bound: probes guarded with p < n
// (batch[n] treated as +inf). R7's failure: e0 search for the last cloud
// read batch[12288] (one past the end) -> phantom candidate j=12288.

#define MAXC 28            // supports cloud <= 1792 (actual ~1536 +- 37)
#define ROWS_PER_BLOCK 4   // 1 row per wave, 256-thread blocks

__device__ __forceinline__ unsigned int map32(float d) {
    unsigned int u = __float_as_uint(d);
    return u ^ (unsigned int)(((int)u >> 31) | 0x80000000);
}

__device__ __forceinline__ unsigned long long map64(double d) {
    unsigned long long u = __double_as_longlong(d);
    return u ^ (unsigned long long)(((long long)u >> 63) |
                                    (long long)0x8000000000000000ull);
}

__device__ __forceinline__ unsigned int umin2(unsigned int a, unsigned int b) {
    return a < b ? a : b;
}

// Full-wave (64-lane) unsigned-min reduction on the VALU pipe via DPP.
// row_shr 1/2/4/8 then row_bcast15 (rows 1,3) + row_bcast31 (rows 2,3);
// old = -1 (umin identity) with bound_ctrl=false so invalid lanes are inert.
__device__ __forceinline__ unsigned int wave_umin_dpp(unsigned int v) {
    int x = (int)v, t;
    t = __builtin_amdgcn_update_dpp(-1, x, 0x111, 0xf, 0xf, false);  // row_shr:1
    x = (int)umin2((unsigned int)x, (unsigned int)t);
    t = __builtin_amdgcn_update_dpp(-1, x, 0x112, 0xf, 0xf, false);  // row_shr:2
    x = (int)umin2((unsigned int)x, (unsigned int)t);
    t = __builtin_amdgcn_update_dpp(-1, x, 0x114, 0xf, 0xf, false);  // row_shr:4
    x = (int)umin2((unsigned int)x, (unsigned int)t);
    t = __builtin_amdgcn_update_dpp(-1, x, 0x118, 0xf, 0xf, false);  // row_shr:8
    x = (int)umin2((unsigned int)x, (unsigned int)t);
    t = __builtin_amdgcn_update_dpp(-1, x, 0x142, 0xa, 0xf, false);  // row_bcast:15
    x = (int)umin2((unsigned int)x, (unsigned int)t);
    t = __builtin_amdgcn_update_dpp(-1, x, 0x143, 0xc, 0xf, false);  // row_bcast:31
    x = (int)umin2((unsigned int)x, (unsigned int)t);
    return (unsigned int)__builtin_amdgcn_readlane(x, 63);
}

// Wave-cooperative lower_bound: first index with arr[idx] >= key, arr sorted,
// result in [0, n]. All probes guarded with p < n (arr[n] == +inf).
__device__ __forceinline__ int wave_lower_bound(const int* __restrict__ arr,
                                                int n, int key, int lane) {
    int lo = 0, len = n;
    while (len > 64) {
        int seg = (len + 63) >> 6;  // ceil(len/64)
        int p = lo + lane * seg;
        bool lt = false;
        if (p < lo + len && p < n) lt = (arr[p] < key);
        int c = (int)__popcll(__ballot(lt));  // contiguous from lane 0 (sorted)
        if (c == 0) return lo;                // arr[lo] >= key
        int nlo = lo + (c - 1) * seg + 1;     // lb >  probe(c-1)
        int hi = lo + c * seg;                // lb <= probe(c) (or window end)
        int wend = lo + len;
        if (hi > wend) hi = wend;
        len = hi + 1 - nlo;
        lo = nlo;
    }
    bool lt = false;
    {
        int p = lo + lane;
        if (lane < len && p < n) lt = (arr[p] < key);
    }
    return lo + (int)__popcll(__ballot(lt));
}

__global__ __launch_bounds__(256) void knn_fused_kernel(
        const float* __restrict__ x,
        const int* __restrict__ batch,
        int k, int n,
        int* __restrict__ out) {
#pragma clang fp contract(off)
    __shared__ int coll[ROWS_PER_BLOCK][64];
    const int wave = threadIdx.x >> 6;
    const int lane = threadIdx.x & 63;
    const int i = blockIdx.x * ROWS_PER_BLOCK + wave;  // one row per wave
    if (i >= n) return;

    const int b = batch[i];
    const int s0 = wave_lower_bound(batch, n, b, lane);
    const int e0 = wave_lower_bound(batch, n, b + 1, lane);

    const float xi0 = x[3 * i + 0];
    const float xi1 = x[3 * i + 1];
    const float xi2 = x[3 * i + 2];
    const float sqi = xi0 * xi0 + xi1 * xi1 + xi2 * xi2;  // plain chain

    // Build u32 value keys (mapped fp32 distance), lane-cyclic layout.
    unsigned int slots[MAXC];
#pragma unroll
    for (int t = 0; t < MAXC; ++t) {
        const int j = s0 + lane + t * 64;
        unsigned int key = 0xFFFFFFFFu;  // pad > any real mapped value
        if (j < e0) {
            const float y0 = x[3 * j + 0];
            const float y1 = x[3 * j + 1];
            const float y2 = x[3 * j + 2];
            const float sqj = y0 * y0 + y1 * y1 + y2 * y2;  // plain chain
            float dot = __builtin_fmaf(xi2, y2,
                        __builtin_fmaf(xi1, y1, xi0 * y0));
            float d = (sqi + sqj) - 2.0f * dot;
            key = map32(d);
        }
        slots[t] = key;
    }

    // Phase 1: k rounds of threshold-ascent distinct-value extract-min.
    // Relative keys (slots[t] - thrp1): already-extracted values wrap to
    // v + 2^32 - thrp1 > any unextracted (v' - thrp1) since v + 2^32 > v'.
    unsigned int thrp1 = 0;  // wave-uniform
    unsigned int T = 0;
    for (int r = 0; r < k; ++r) {
        unsigned int m0 = slots[0] - thrp1, m1 = slots[1] - thrp1;
        unsigned int m2 = slots[2] - thrp1, m3 = slots[3] - thrp1;
#pragma unroll
        for (int t = 4; t < MAXC; t += 4) {
            m0 = umin2(m0, slots[t + 0] - thrp1);
            m1 = umin2(m1, slots[t + 1] - thrp1);
            m2 = umin2(m2, slots[t + 2] - thrp1);
            m3 = umin2(m3, slots[t + 3] - thrp1);
        }
        unsigned int lm = umin2(umin2(m0, m1), umin2(m2, m3));
        unsigned int rel = wave_umin_dpp(lm);
        T = rel + thrp1;
        thrp1 = T + 1;
    }

    // Phase 2: compact indices of candidates with key <= T into LDS.
    int base = 0;
#pragma unroll
    for (int t = 0; t < MAXC; ++t) {
        const int j = s0 + lane + t * 64;
        bool hit = (slots[t] <= T);  // pad 0xFFFFFFFF > T always
        unsigned long long bal = __ballot(hit);
        int off = base + __builtin_amdgcn_mbcnt_hi(
                             (unsigned int)(bal >> 32),
                             __builtin_amdgcn_mbcnt_lo((unsigned int)bal, 0));
        if (hit && off < 64) coll[wave][off] = j;
        base += (int)__popcll(bal);
    }
    const int cnt = base < 64 ? base : 64;  // wave-uniform

    // Phase 3: refinement — rank collected by (fp32key, fp64 dist, idx).
    const bool valid = (lane < cnt);
    const int idx = valid ? coll[wave][lane] : 0;
    unsigned int v32 = 0xFFFFFFFFu;
    unsigned long long m64 = ~0ull;
    if (valid) {
        const float y0 = x[3 * idx + 0];
        const float y1 = x[3 * idx + 1];
        const float y2 = x[3 * idx + 2];
        const float sqj = y0 * y0 + y1 * y1 + y2 * y2;
        float dot = __builtin_fmaf(xi2, y2,
                    __builtin_fmaf(xi1, y1, xi0 * y0));
        float d = (sqi + sqj) - 2.0f * dot;
        v32 = map32(d);
        // exact fp64 (products of fp32 are exact in double)
        double q0 = (double)xi0 * (double)xi0;
        double q1 = (double)xi1 * (double)xi1;
        double q2 = (double)xi2 * (double)xi2;
        double sqdi = (q0 + q1) + q2;
        double w0 = (double)y0 * (double)y0;
        double w1 = (double)y1 * (double)y1;
        double w2 = (double)y2 * (double)y2;
        double sqdj = (w0 + w1) + w2;
        double p0 = (double)xi0 * (double)y0;
        double p1 = (double)xi1 * (double)y1;
        double p2 = (double)xi2 * (double)y2;
        double dot64 = (p0 + p1) + p2;
        double d64 = (sqdi + sqdj) - 2.0 * dot64;
        m64 = map64(d64);
    }

    int pos = 0;
    for (int s = 0; s < cnt; ++s) {
        unsigned int vs = (unsigned int)__shfl((int)v32, s);
        unsigned long long ms = __shfl(m64, s);
        int is_ = __shfl(idx, s);
        bool less = (vs < v32) ||
                    (vs == v32 && (ms < m64 || (ms == m64 && is_ < idx)));
        pos += less ? 1 : 0;
    }

    if (valid && pos < k) out[(long long)i * k + pos] = idx;
}

extern "C" void kernel_launch(void* const* d_in, const int* in_sizes, int n_in,
                              void* d_out, int out_size, void* d_ws, size_t ws_size,
                              hipStream_t stream) {
    const float* x = (const float*)d_in[0];
    const int* batch = (const int*)d_in[1];
    const int n = in_sizes[1];            // 12288 points
    const int k = out_size / n;           // 20
    int* out = (int*)d_out;

    const int blocks = (n + ROWS_PER_BLOCK - 1) / ROWS_PER_BLOCK;
    knn_fused_kernel<<<blocks, 64 * ROWS_PER_BLOCK, 0, stream>>>(x, batch, k, n, out);
}